// Round 13
// baseline (30.051 us; speedup 1.0000x reference)
//
#include <hip/hip_runtime.h>

typedef __bf16 bf16x8 __attribute__((ext_vector_type(8)));
typedef float  f32x4  __attribute__((ext_vector_type(4)));

__device__ __forceinline__ unsigned short f2bf(float f) {
    unsigned int u = __float_as_uint(f);
    u += 0x7FFF + ((u >> 16) & 1);          // RNE
    return (unsigned short)(u >> 16);
}
__device__ __forceinline__ unsigned int pk2bf(float a, float b) {
    return (unsigned int)f2bf(a) | ((unsigned int)f2bf(b) << 16);
}

#define GLD_LDS16(gptr, lptr) \
    __builtin_amdgcn_global_load_lds((const __attribute__((address_space(1))) void*)(gptr), \
                                     (__attribute__((address_space(3))) void*)(lptr), 16, 0, 0)

// ===== K1: blocks [0,64)  : small GEMM wcT=(wv@wp)^T, fp32 weights inline-converted
//           (coalesced B-transpose loads + packed ds_write_b128, BK=128, reg dbuf)
//           blocks [64,320): partial sums of x (32-row chunks) -> part
__global__ __launch_bounds__(256) void k1_gemm_partial(
    const float* __restrict__ x, const float* __restrict__ w_attn,
    const float* __restrict__ w_proj,
    unsigned short* __restrict__ wcT, float* __restrict__ part)
{
    __shared__ __align__(16) unsigned short As[2][64 * 128];   // 32 KB
    __shared__ __align__(16) unsigned short Bs[2][64 * 128];   // 32 KB
    const int bid = blockIdx.x, tid = threadIdx.x;

    if (bid < 64) {
        // bm shared within an XCD (bid%8 = XCD on default round-robin)
        const int bm = (bid & 7) * 64, bn = (bid >> 3) * 64;
        const int lane = tid & 63, w = tid >> 6, wm = w >> 1, wn = w & 1;
        const int arow = lane & 15, kg = lane >> 4;

        const int r_a  = tid >> 2;        // A: row 0..63
        const int ca   = tid & 3;         // A: chunk slot
        const int jl   = tid & 63;        // B: output col (lane -> coalesced)
        const int kslw = tid >> 6;        // B: chunk slot (= wave)

        float4 aR[4][2];
        float  bR[4][8];

        auto load_regs = [&](int kt) {
            const float* ap = w_attn + (size_t)(bm + r_a) * 1536 + 1024 + kt * 128;
            #pragma unroll
            for (int i = 0; i < 4; ++i) {
                const int c = ca + 4 * i;
                aR[i][0] = *(const float4*)(ap + c * 8);
                aR[i][1] = *(const float4*)(ap + c * 8 + 4);
            }
            const float* bp = w_proj + (size_t)(kt * 128) * 512 + bn + jl;
            #pragma unroll
            for (int i = 0; i < 4; ++i) {
                const int c = kslw + 4 * i;
                #pragma unroll
                for (int s = 0; s < 8; ++s)
                    bR[i][s] = bp[(size_t)(c * 8 + s) * 512];   // coalesced across lanes
            }
        };
        auto cvt_write = [&](int buf) {
            char* amem = (char*)As[buf];
            #pragma unroll
            for (int i = 0; i < 4; ++i) {
                const int c = ca + 4 * i;
                uint4 pk;
                pk.x = pk2bf(aR[i][0].x, aR[i][0].y);
                pk.y = pk2bf(aR[i][0].z, aR[i][0].w);
                pk.z = pk2bf(aR[i][1].x, aR[i][1].y);
                pk.w = pk2bf(aR[i][1].z, aR[i][1].w);
                *(uint4*)(amem + r_a * 256 + ((c ^ (r_a & 15)) << 4)) = pk;
            }
            char* bmem = (char*)Bs[buf];
            #pragma unroll
            for (int i = 0; i < 4; ++i) {
                const int c = kslw + 4 * i;
                uint4 pk;
                pk.x = pk2bf(bR[i][0], bR[i][1]);
                pk.y = pk2bf(bR[i][2], bR[i][3]);
                pk.z = pk2bf(bR[i][4], bR[i][5]);
                pk.w = pk2bf(bR[i][6], bR[i][7]);
                *(uint4*)(bmem + jl * 256 + ((c ^ (jl & 15)) << 4)) = pk;
            }
        };

        int offA[2][4], offB[2][4];
        #pragma unroll
        for (int f = 0; f < 2; ++f)
            #pragma unroll
            for (int kk = 0; kk < 4; ++kk) {
                offA[f][kk] = (wm * 32 + f * 16 + arow) * 256 + (((kk * 4 + kg) ^ arow) << 4);
                offB[f][kk] = (wn * 32 + f * 16 + arow) * 256 + (((kk * 4 + kg) ^ arow) << 4);
            }

        f32x4 acc[2][2] = {};
        load_regs(0); cvt_write(0); __syncthreads();
        #pragma unroll
        for (int kt = 0; kt < 4; ++kt) {
            const int buf = kt & 1;
            if (kt < 3) load_regs(kt + 1);
            const char* la = (const char*)As[buf];
            const char* lb = (const char*)Bs[buf];
            #pragma unroll
            for (int kk = 0; kk < 4; ++kk) {
                bf16x8 a0 = *(const bf16x8*)(la + offA[0][kk]);
                bf16x8 a1 = *(const bf16x8*)(la + offA[1][kk]);
                bf16x8 b0 = *(const bf16x8*)(lb + offB[0][kk]);
                bf16x8 b1 = *(const bf16x8*)(lb + offB[1][kk]);
                acc[0][0] = __builtin_amdgcn_mfma_f32_16x16x32_bf16(a0, b0, acc[0][0], 0, 0, 0);
                acc[0][1] = __builtin_amdgcn_mfma_f32_16x16x32_bf16(a0, b1, acc[0][1], 0, 0, 0);
                acc[1][0] = __builtin_amdgcn_mfma_f32_16x16x32_bf16(a1, b0, acc[1][0], 0, 0, 0);
                acc[1][1] = __builtin_amdgcn_mfma_f32_16x16x32_bf16(a1, b1, acc[1][1], 0, 0, 0);
            }
            __syncthreads();
            if (kt < 3) { cvt_write(buf ^ 1); __syncthreads(); }
        }
        #pragma unroll
        for (int fm = 0; fm < 2; ++fm)
            #pragma unroll
            for (int fn = 0; fn < 2; ++fn) {
                const int row0 = bm + wm * 32 + fm * 16 + kg * 4;
                const int col  = bn + wn * 32 + fn * 16 + arow;
                ushort4 pk;
                pk.x = f2bf(acc[fm][fn][0]);
                pk.y = f2bf(acc[fm][fn][1]);
                pk.z = f2bf(acc[fm][fn][2]);
                pk.w = f2bf(acc[fm][fn][3]);
                *(ushort4*)(&wcT[(size_t)col * 512 + row0]) = pk;   // C^T
            }
    } else {
        const int bx = bid - 64;              // 0..255
        const int b  = bx >> 7;
        const int ch = (bx >> 1) & 63;
        const int j  = (bx & 1) * 256 + tid;
        const float* p = x + ((size_t)b * 2048 + ch * 32) * 512 + j;
        float s = 0.f;
        #pragma unroll 8
        for (int t = 0; t < 32; ++t) s += p[(size_t)t * 512];
        part[((size_t)b * 64 + ch) * 512 + j] = s;
    }
}

// ===== K2: fused scan + big GEMM. 512 blocks = 64 mt x 8 nt (XCD-chunked), 80 KB LDS,
// 2 blocks/CU. Prologue: masked fixed-trip prefix + 64-row cumsum -> swizzled resident
// A-tile. Main loop: 8 kt steps, B double-buffered via gld_lds, counted vmcnt(2).
__global__ __launch_bounds__(256) void k2_fused(
    const float* __restrict__ x,
    const unsigned short* __restrict__ wcT,
    const float* __restrict__ part,
    float* __restrict__ y)
{
    __shared__ __align__(16) unsigned short Atile[64 * 512];   // 64 KB
    __shared__ __align__(16) unsigned short Bs[2][64 * 64];    // 16 KB

    const int bid = blockIdx.x;            // 0..511
    const int xcd = bid & 7, idx = bid >> 3;
    const int mt  = xcd * 8 + (idx >> 3);  // 8 mt panels per XCD (x L2-shared)
    const int nt  = idx & 7;

    const int tid  = threadIdx.x;
    const int lane = tid & 63, w = tid >> 6, wm = w >> 1, wn = w & 1;
    const int arow = lane & 15, kg = lane >> 4;

    // --- B staging (r9-proven 64x64 path), first two tiles issued before prologue
    const int srow   = w * 16 + (lane >> 3);
    const int schunk = (lane & 7) ^ (lane >> 3);
    const unsigned short* gB = wcT + (size_t)(nt * 64 + srow) * 512 + schunk * 8;
    auto stageB = [&](int buf, int kt) {
        GLD_LDS16(gB + kt * 64,                   Bs[buf] + (w * 16 + 0) * 64);
        GLD_LDS16(gB + (size_t)8 * 512 + kt * 64, Bs[buf] + (w * 16 + 8) * 64);
    };
    stageB(0, 0);
    stageB(1, 1);

    // --- prologue: prefix (masked fixed-trip, pipelined) + 64-row cumsum -> Atile
    const int b = mt >> 5, c2 = (mt & 31) * 2;
    const int k0 = tid * 2;
    float rx = 0.f, ry = 0.f;
    #pragma unroll 8
    for (int cc = 0; cc < 62; ++cc) {
        float2 v = *(const float2*)(part + ((size_t)b * 64 + cc) * 512 + k0);
        rx += (cc < c2) ? v.x : 0.f;
        ry += (cc < c2) ? v.y : 0.f;
    }
    {
        const float* xp = x + (size_t)mt * 64 * 512 + k0;
        const int cbase = tid >> 2;
        const int sub   = (tid & 3) * 4;
        #pragma unroll 8
        for (int t = 0; t < 64; ++t) {
            float2 v = *(const float2*)(xp + (size_t)t * 512);
            rx += v.x; ry += v.y;
            const float inv = 1.0f / (float)((mt & 31) * 64 + t + 1);
            *(unsigned int*)((char*)Atile + t * 1024 + ((cbase ^ (t & 7)) << 4) + sub)
                = pk2bf(rx * inv, ry * inv);
        }
    }
    asm volatile("s_waitcnt lgkmcnt(0)" ::: "memory");
    __builtin_amdgcn_s_barrier();          // Atile complete

    int offA[2][2], offB[2][2];
    #pragma unroll
    for (int f = 0; f < 2; ++f)
        #pragma unroll
        for (int kk = 0; kk < 2; ++kk) {
            offA[f][kk] = (wm * 32 + f * 16 + arow) * 1024 + (((kk * 4 + kg) ^ (arow & 7)) << 4);
            offB[f][kk] = (wn * 32 + f * 16 + arow) * 128  + (((kk * 4 + kg) ^ (arow & 7)) << 4);
        }

    f32x4 acc[2][2] = {};
    #pragma unroll
    for (int kt = 0; kt < 8; ++kt) {
        const int buf = kt & 1;
        if (kt < 7) asm volatile("s_waitcnt vmcnt(2)" ::: "memory");   // kt landed, kt+1 in flight
        else        asm volatile("s_waitcnt vmcnt(0)" ::: "memory");
        __builtin_amdgcn_s_barrier();
        const char* la = (const char*)Atile + kt * 128;   // kt's 8-chunk group
        const char* lb = (const char*)Bs[buf];
        #pragma unroll
        for (int kk = 0; kk < 2; ++kk) {
            bf16x8 a0 = *(const bf16x8*)(la + offA[0][kk]);
            bf16x8 a1 = *(const bf16x8*)(la + offA[1][kk]);
            bf16x8 b0 = *(const bf16x8*)(lb + offB[0][kk]);
            bf16x8 b1 = *(const bf16x8*)(lb + offB[1][kk]);
            acc[0][0] = __builtin_amdgcn_mfma_f32_16x16x32_bf16(a0, b0, acc[0][0], 0, 0, 0);
            acc[0][1] = __builtin_amdgcn_mfma_f32_16x16x32_bf16(a0, b1, acc[0][1], 0, 0, 0);
            acc[1][0] = __builtin_amdgcn_mfma_f32_16x16x32_bf16(a1, b0, acc[1][0], 0, 0, 0);
            acc[1][1] = __builtin_amdgcn_mfma_f32_16x16x32_bf16(a1, b1, acc[1][1], 0, 0, 0);
        }
        __builtin_amdgcn_s_barrier();                     // reads done before overwrite
        if (kt < 6) stageB(buf, kt + 2);
    }

    #pragma unroll
    for (int fm = 0; fm < 2; ++fm)
        #pragma unroll
        for (int fn = 0; fn < 2; ++fn) {
            const int row0 = mt * 64 + wm * 32 + fm * 16 + kg * 4;
            const int col  = nt * 64 + wn * 32 + fn * 16 + arow;
            #pragma unroll
            for (int r = 0; r < 4; ++r)
                y[(size_t)(row0 + r) * 512 + col] = acc[fm][fn][r];
        }
}

extern "C" void kernel_launch(void* const* d_in, const int* in_sizes, int n_in,
                              void* d_out, int out_size, void* d_ws, size_t ws_size,
                              hipStream_t stream)
{
    const float* x      = (const float*)d_in[0];   // (2,2048,512) fp32
    const float* w_attn = (const float*)d_in[1];   // (512,1536); V = cols [1024,1536)
    const float* w_proj = (const float*)d_in[2];   // (512,512)
    float* y = (float*)d_out;

    unsigned short* wcT = (unsigned short*)d_ws;    // [512][512] bf16 ((wv@wp)^T)
    float* part = (float*)(wcT + 512 * 512);        // [2][64][512] f32 (32-row chunk sums)

    k1_gemm_partial<<<320, 256, 0, stream>>>(x, w_attn, w_proj, wcT, part);
    k2_fused<<<512, 256, 0, stream>>>(x, wcT, part, y);
}

// Round 14
// 27.022 us; speedup vs baseline: 1.1121x; 1.1121x over previous
//
#include <hip/hip_runtime.h>

typedef __bf16 bf16x8 __attribute__((ext_vector_type(8)));
typedef float  f32x4  __attribute__((ext_vector_type(4)));

__device__ __forceinline__ unsigned short f2bf(float f) {
    unsigned int u = __float_as_uint(f);
    u += 0x7FFF + ((u >> 16) & 1);          // RNE
    return (unsigned short)(u >> 16);
}

#define GLD_LDS16(gptr, lptr) \
    __builtin_amdgcn_global_load_lds((const __attribute__((address_space(1))) void*)(gptr), \
                                     (__attribute__((address_space(3))) void*)(lptr), 16, 0, 0)

// ---- r12-proven 64x64-tile bf16 GEMM body, BK=128, 2-deep prefetch + counted vmcnt.
// Used by the small GEMM only. EPI=1: Cout=bf16 [512][512] transposed (C^T).
template<int EPI>
__device__ __forceinline__ void gemm_tile(const unsigned short* __restrict__ A,
                                          const unsigned short* __restrict__ Bt,
                                          void* __restrict__ Cout,
                                          unsigned short* lds,
                                          int bm, int bn)
{
    const int tid  = threadIdx.x;
    const int lane = tid & 63;
    const int w    = tid >> 6;
    const int wm   = w >> 1, wn = w & 1;
    const int arow = lane & 15;
    const int kg   = lane >> 4;

    const int srow   = tid >> 4;                 // row within 16-row group
    const int schunk = (tid & 15) ^ srow;        // inverse-swizzle on SOURCE
    const unsigned short* gA = A  + (size_t)(bm + srow) * 512 + schunk * 8;
    const unsigned short* gB = Bt + (size_t)(bn + srow) * 512 + schunk * 8;

    auto stage = [&](int buf, int kt) {
        unsigned short* la = lds + buf * 16384;
        unsigned short* lb = la + 8192;
        const int k0 = kt * 128;
        #pragma unroll
        for (int i = 0; i < 4; ++i) {
            GLD_LDS16(gA + (size_t)(i * 16) * 512 + k0, la + i * 2048 + w * 512);
            GLD_LDS16(gB + (size_t)(i * 16) * 512 + k0, lb + i * 2048 + w * 512);
        }
    };

    int offA[2][4], offB[2][4];
    #pragma unroll
    for (int f = 0; f < 2; ++f)
        #pragma unroll
        for (int kk = 0; kk < 4; ++kk) {
            offA[f][kk] = (wm * 32 + f * 16 + arow) * 256 + (((kk * 4 + kg) ^ arow) << 4);
            offB[f][kk] = (wn * 32 + f * 16 + arow) * 256 + (((kk * 4 + kg) ^ arow) << 4);
        }

    stage(0, 0);
    stage(1, 1);

    f32x4 acc[2][2] = {};
    #pragma unroll
    for (int kt = 0; kt < 4; ++kt) {
        const int buf = kt & 1;
        if (kt < 3) asm volatile("s_waitcnt vmcnt(8)" ::: "memory");
        else        asm volatile("s_waitcnt vmcnt(0)" ::: "memory");
        __builtin_amdgcn_s_barrier();
        const char* la = (const char*)(lds + buf * 16384);
        const char* lb = la + 16384;
        #pragma unroll
        for (int kk = 0; kk < 4; ++kk) {
            bf16x8 a0 = *(const bf16x8*)(la + offA[0][kk]);
            bf16x8 a1 = *(const bf16x8*)(la + offA[1][kk]);
            bf16x8 b0 = *(const bf16x8*)(lb + offB[0][kk]);
            bf16x8 b1 = *(const bf16x8*)(lb + offB[1][kk]);
            acc[0][0] = __builtin_amdgcn_mfma_f32_16x16x32_bf16(a0, b0, acc[0][0], 0, 0, 0);
            acc[0][1] = __builtin_amdgcn_mfma_f32_16x16x32_bf16(a0, b1, acc[0][1], 0, 0, 0);
            acc[1][0] = __builtin_amdgcn_mfma_f32_16x16x32_bf16(a1, b0, acc[1][0], 0, 0, 0);
            acc[1][1] = __builtin_amdgcn_mfma_f32_16x16x32_bf16(a1, b1, acc[1][1], 0, 0, 0);
        }
        __builtin_amdgcn_s_barrier();
        if (kt < 2) stage(buf, kt + 2);
    }

    #pragma unroll
    for (int fm = 0; fm < 2; ++fm)
        #pragma unroll
        for (int fn = 0; fn < 2; ++fn) {
            const int row0 = bm + wm * 32 + fm * 16 + kg * 4;
            const int col  = bn + wn * 32 + fn * 16 + arow;
            if (EPI == 0) {
                float* C = (float*)Cout;
                #pragma unroll
                for (int r = 0; r < 4; ++r)
                    C[(size_t)(row0 + r) * 512 + col] = acc[fm][fn][r];
            } else {
                unsigned short* C = (unsigned short*)Cout;   // C^T
                ushort4 pk;
                pk.x = f2bf(acc[fm][fn][0]);
                pk.y = f2bf(acc[fm][fn][1]);
                pk.z = f2bf(acc[fm][fn][2]);
                pk.w = f2bf(acc[fm][fn][3]);
                *(ushort4*)(&C[(size_t)col * 512 + row0]) = pk;
            }
        }
}

// K1 (r12 verbatim): blocks [0,64) transpose w_proj -> wpT; [64,128) wv convert;
// [128,384) partial sums of x.
__global__ __launch_bounds__(256) void k1_prep_partial(
    const float* __restrict__ x, const float* __restrict__ w_attn,
    const float* __restrict__ w_proj,
    unsigned short* __restrict__ wv, unsigned short* __restrict__ wpT,
    float* __restrict__ part)
{
    __shared__ float ls[64][65];
    const int bid = blockIdx.x, tid = threadIdx.x;

    if (bid < 64) {
        const int m0 = (bid >> 3) * 64;
        const int j0 = (bid & 7) * 64;
        const int rr = tid >> 4;
        const int c4 = (tid & 15) * 4;
        #pragma unroll
        for (int i = 0; i < 4; ++i) {
            float4 v = *(const float4*)(w_proj + (size_t)(m0 + rr + 16 * i) * 512 + j0 + c4);
            ls[rr + 16 * i][c4 + 0] = v.x;
            ls[rr + 16 * i][c4 + 1] = v.y;
            ls[rr + 16 * i][c4 + 2] = v.z;
            ls[rr + 16 * i][c4 + 3] = v.w;
        }
        __syncthreads();
        const int c    = tid >> 2;
        const int mgrp = (tid & 3) * 16;
        #pragma unroll
        for (int u = 0; u < 4; ++u) {
            const int m = mgrp + u * 4;
            ushort4 o;
            o.x = f2bf(ls[m + 0][c]);
            o.y = f2bf(ls[m + 1][c]);
            o.z = f2bf(ls[m + 2][c]);
            o.w = f2bf(ls[m + 3][c]);
            *(ushort4*)(wpT + (size_t)(j0 + c) * 512 + m0 + m) = o;
        }
    } else if (bid < 128) {
        const int bb = bid - 64;
        #pragma unroll
        for (int i = 0; i < 4; ++i) {
            const int flat = bb * 1024 + i * 256 + tid;
            const int ir = flat >> 7;
            const int m4 = (flat & 127) * 4;
            float4 v = *(const float4*)(w_attn + (size_t)ir * 1536 + 1024 + m4);
            ushort4 o;
            o.x = f2bf(v.x); o.y = f2bf(v.y); o.z = f2bf(v.z); o.w = f2bf(v.w);
            *(ushort4*)(wv + (size_t)ir * 512 + m4) = o;
        }
    } else {
        const int bx = bid - 128;
        const int b  = bx >> 7;
        const int ch = (bx >> 1) & 63;
        const int j  = (bx & 1) * 256 + tid;
        const float* p = x + ((size_t)b * 2048 + ch * 32) * 512 + j;
        float s = 0.f;
        #pragma unroll 8
        for (int t = 0; t < 32; ++t) s += p[(size_t)t * 512];
        part[((size_t)b * 64 + ch) * 512 + j] = s;
    }
}

// K2 (r12 verbatim): blocks [0,64) small GEMM; [64,320) finalize -> s16
__global__ __launch_bounds__(256) void k2_smallgemm_finalize(
    const float* __restrict__ x,
    const unsigned short* __restrict__ wv, const unsigned short* __restrict__ wpT,
    const float* __restrict__ part,
    unsigned short* __restrict__ wcT, unsigned short* __restrict__ s16)
{
    __shared__ __align__(16) unsigned short lds[2 * 16384];   // 64 KB
    const int bid = blockIdx.x, tid = threadIdx.x;

    if (bid < 64) {
        gemm_tile<1>(wv, wpT, wcT, lds, (bid >> 3) * 64, (bid & 7) * 64);
    } else {
        const int bx = bid - 64;
        const int b  = bx >> 7;
        const int ch = (bx >> 1) & 63;
        const int j  = (bx & 1) * 256 + tid;
        float run = 0.f;
        #pragma unroll 8
        for (int cc = 0; cc < 63; ++cc) {
            float v = part[((size_t)b * 64 + cc) * 512 + j];
            run += (cc < ch) ? v : 0.f;
        }
        const float*    p = x   + ((size_t)b * 2048 + ch * 32) * 512 + j;
        unsigned short* q = s16 + ((size_t)b * 2048 + ch * 32) * 512 + j;
        #pragma unroll 8
        for (int t = 0; t < 32; ++t) {
            run += p[(size_t)t * 512];
            q[(size_t)t * 512] = f2bf(run * (1.0f / (float)(ch * 32 + t + 1)));
        }
    }
}

// K3 (NEW): y = s16 @ wcT^T, 128x64 tiles, BK=64, 256 blocks, 48 KB LDS -> 3 blocks/CU.
// 4 waves = 2m x 2n, wave tile 64x32 = 4x2 frags. 2-deep prefetch, counted vmcnt(6).
__global__ __launch_bounds__(256) void k3_biggemm(
    const unsigned short* __restrict__ s16,
    const unsigned short* __restrict__ wcT,
    float* __restrict__ y)
{
    __shared__ __align__(16) unsigned short As[2][128 * 64];   // 32 KB
    __shared__ __align__(16) unsigned short Bs[2][64 * 64];    // 16 KB

    const int bid = blockIdx.x;             // 0..255
    const int xcd = bid & 7, idx = bid >> 3;
    const int mt  = xcd * 4 + (idx >> 3);   // 0..31: 4 contiguous m-strips per XCD
    const int nt  = idx & 7;                // 0..7

    const int tid  = threadIdx.x;
    const int lane = tid & 63, w = tid >> 6;
    const int wm   = w >> 1, wn = w & 1;
    const int arow = lane & 15, kg = lane >> 4;

    // staging: row = i*32 + (tid>>3), chunk = lane&7, source pre-swizzled (involution)
    const int srow   = tid >> 3;                    // 0..31
    const int schunk = (lane & 7) ^ (lane >> 3);
    const unsigned short* gA = s16 + (size_t)(mt * 128 + srow) * 512 + schunk * 8;
    const unsigned short* gB = wcT + (size_t)(nt * 64  + srow) * 512 + schunk * 8;

    auto stage = [&](int buf, int kt) {             // 6 gld_lds per call
        const int k0 = kt * 64;
        unsigned short* la = As[buf];
        unsigned short* lb = Bs[buf];
        #pragma unroll
        for (int i = 0; i < 4; ++i)
            GLD_LDS16(gA + (size_t)(i * 32) * 512 + k0, la + i * 2048 + w * 512);
        #pragma unroll
        for (int i = 0; i < 2; ++i)
            GLD_LDS16(gB + (size_t)(i * 32) * 512 + k0, lb + i * 2048 + w * 512);
    };

    // read offsets: row stride 128B (8 chunks of 16B), XOR chunk ^ (row&7)
    int offA[4][2], offB[2][2];
    #pragma unroll
    for (int f = 0; f < 4; ++f)
        #pragma unroll
        for (int kk = 0; kk < 2; ++kk)
            offA[f][kk] = (wm * 64 + f * 16 + arow) * 128 + (((kk * 4 + kg) ^ (arow & 7)) << 4);
    #pragma unroll
    for (int g = 0; g < 2; ++g)
        #pragma unroll
        for (int kk = 0; kk < 2; ++kk)
            offB[g][kk] = (wn * 32 + g * 16 + arow) * 128 + (((kk * 4 + kg) ^ (arow & 7)) << 4);

    stage(0, 0);
    stage(1, 1);                                    // 12 outstanding

    f32x4 acc[4][2] = {};
    #pragma unroll
    for (int kt = 0; kt < 8; ++kt) {
        const int buf = kt & 1;
        if (kt < 7) asm volatile("s_waitcnt vmcnt(6)" ::: "memory");   // kt landed, kt+1 in flight
        else        asm volatile("s_waitcnt vmcnt(0)" ::: "memory");
        __builtin_amdgcn_s_barrier();
        const char* la = (const char*)As[buf];
        const char* lb = (const char*)Bs[buf];
        #pragma unroll
        for (int kk = 0; kk < 2; ++kk) {
            bf16x8 b0 = *(const bf16x8*)(lb + offB[0][kk]);
            bf16x8 b1 = *(const bf16x8*)(lb + offB[1][kk]);
            #pragma unroll
            for (int f = 0; f < 4; ++f) {
                bf16x8 af = *(const bf16x8*)(la + offA[f][kk]);
                acc[f][0] = __builtin_amdgcn_mfma_f32_16x16x32_bf16(af, b0, acc[f][0], 0, 0, 0);
                acc[f][1] = __builtin_amdgcn_mfma_f32_16x16x32_bf16(af, b1, acc[f][1], 0, 0, 0);
            }
        }
        __builtin_amdgcn_s_barrier();
        if (kt < 6) stage(buf, kt + 2);
    }

    #pragma unroll
    for (int f = 0; f < 4; ++f)
        #pragma unroll
        for (int g = 0; g < 2; ++g) {
            const int row0 = mt * 128 + wm * 64 + f * 16 + kg * 4;
            const int col  = nt * 64  + wn * 32 + g * 16 + arow;
            #pragma unroll
            for (int r = 0; r < 4; ++r)
                y[(size_t)(row0 + r) * 512 + col] = acc[f][g][r];
        }
}

extern "C" void kernel_launch(void* const* d_in, const int* in_sizes, int n_in,
                              void* d_out, int out_size, void* d_ws, size_t ws_size,
                              hipStream_t stream)
{
    const float* x      = (const float*)d_in[0];   // (2,2048,512)
    const float* w_attn = (const float*)d_in[1];   // (512,1536); V = cols [1024,1536)
    const float* w_proj = (const float*)d_in[2];   // (512,512)
    float* y = (float*)d_out;

    unsigned short* wv  = (unsigned short*)d_ws;       // [512][512] bf16
    unsigned short* wpT = wv  + 512 * 512;             // [512][512] bf16 (w_proj^T)
    unsigned short* wcT = wpT + 512 * 512;             // [512][512] bf16 ((wv@wp)^T)
    unsigned short* s16 = wcT + 512 * 512;             // [4096][512] bf16
    float* part = (float*)(s16 + (size_t)4096 * 512);  // [2][64][512] f32

    k1_prep_partial<<<384, 256, 0, stream>>>(x, w_attn, w_proj, wv, wpT, part);
    k2_smallgemm_finalize<<<320, 256, 0, stream>>>(x, wv, wpT, part, wcT, s16);
    k3_biggemm<<<256, 256, 0, stream>>>(s16, wcT, y);
}

// Round 15
// 25.756 us; speedup vs baseline: 1.1668x; 1.0491x over previous
//
#include <hip/hip_runtime.h>

typedef __bf16 bf16x8 __attribute__((ext_vector_type(8)));
typedef float  f32x4  __attribute__((ext_vector_type(4)));

__device__ __forceinline__ unsigned short f2bf(float f) {
    unsigned int u = __float_as_uint(f);
    u += 0x7FFF + ((u >> 16) & 1);          // RNE
    return (unsigned short)(u >> 16);
}
__device__ __forceinline__ unsigned int pk2bf(float a, float b) {
    return (unsigned int)f2bf(a) | ((unsigned int)f2bf(b) << 16);
}

#define GLD_LDS16(gptr, lptr) \
    __builtin_amdgcn_global_load_lds((const __attribute__((address_space(1))) void*)(gptr), \
                                     (__attribute__((address_space(3))) void*)(lptr), 16, 0, 0)

// ---- r12-proven 64x64-tile bf16 GEMM body, BK=128, 2-deep prefetch + counted vmcnt.
// EPI=0: Cout=float[M][512] row-major. EPI=1: Cout=bf16 [512][512] transposed (C^T).
template<int EPI>
__device__ __forceinline__ void gemm_tile(const unsigned short* __restrict__ A,
                                          const unsigned short* __restrict__ Bt,
                                          void* __restrict__ Cout,
                                          unsigned short* lds,
                                          int bm, int bn)
{
    const int tid  = threadIdx.x;
    const int lane = tid & 63;
    const int w    = tid >> 6;
    const int wm   = w >> 1, wn = w & 1;
    const int arow = lane & 15;
    const int kg   = lane >> 4;

    const int srow   = tid >> 4;                 // row within 16-row group
    const int schunk = (tid & 15) ^ srow;        // inverse-swizzle on SOURCE
    const unsigned short* gA = A  + (size_t)(bm + srow) * 512 + schunk * 8;
    const unsigned short* gB = Bt + (size_t)(bn + srow) * 512 + schunk * 8;

    auto stage = [&](int buf, int kt) {
        unsigned short* la = lds + buf * 16384;
        unsigned short* lb = la + 8192;
        const int k0 = kt * 128;
        #pragma unroll
        for (int i = 0; i < 4; ++i) {
            GLD_LDS16(gA + (size_t)(i * 16) * 512 + k0, la + i * 2048 + w * 512);
            GLD_LDS16(gB + (size_t)(i * 16) * 512 + k0, lb + i * 2048 + w * 512);
        }
    };

    int offA[2][4], offB[2][4];
    #pragma unroll
    for (int f = 0; f < 2; ++f)
        #pragma unroll
        for (int kk = 0; kk < 4; ++kk) {
            offA[f][kk] = (wm * 32 + f * 16 + arow) * 256 + (((kk * 4 + kg) ^ arow) << 4);
            offB[f][kk] = (wn * 32 + f * 16 + arow) * 256 + (((kk * 4 + kg) ^ arow) << 4);
        }

    stage(0, 0);
    stage(1, 1);

    f32x4 acc[2][2] = {};
    #pragma unroll
    for (int kt = 0; kt < 4; ++kt) {
        const int buf = kt & 1;
        if (kt < 3) asm volatile("s_waitcnt vmcnt(8)" ::: "memory");
        else        asm volatile("s_waitcnt vmcnt(0)" ::: "memory");
        __builtin_amdgcn_s_barrier();
        const char* la = (const char*)(lds + buf * 16384);
        const char* lb = la + 16384;
        #pragma unroll
        for (int kk = 0; kk < 4; ++kk) {
            bf16x8 a0 = *(const bf16x8*)(la + offA[0][kk]);
            bf16x8 a1 = *(const bf16x8*)(la + offA[1][kk]);
            bf16x8 b0 = *(const bf16x8*)(lb + offB[0][kk]);
            bf16x8 b1 = *(const bf16x8*)(lb + offB[1][kk]);
            acc[0][0] = __builtin_amdgcn_mfma_f32_16x16x32_bf16(a0, b0, acc[0][0], 0, 0, 0);
            acc[0][1] = __builtin_amdgcn_mfma_f32_16x16x32_bf16(a0, b1, acc[0][1], 0, 0, 0);
            acc[1][0] = __builtin_amdgcn_mfma_f32_16x16x32_bf16(a1, b0, acc[1][0], 0, 0, 0);
            acc[1][1] = __builtin_amdgcn_mfma_f32_16x16x32_bf16(a1, b1, acc[1][1], 0, 0, 0);
        }
        __builtin_amdgcn_s_barrier();
        if (kt < 2) stage(buf, kt + 2);
    }

    #pragma unroll
    for (int fm = 0; fm < 2; ++fm)
        #pragma unroll
        for (int fn = 0; fn < 2; ++fn) {
            const int row0 = bm + wm * 32 + fm * 16 + kg * 4;
            const int col  = bn + wn * 32 + fn * 16 + arow;
            if (EPI == 0) {
                float* C = (float*)Cout;
                #pragma unroll
                for (int r = 0; r < 4; ++r)
                    C[(size_t)(row0 + r) * 512 + col] = acc[fm][fn][r];
            } else {
                unsigned short* C = (unsigned short*)Cout;   // C^T
                ushort4 pk;
                pk.x = f2bf(acc[fm][fn][0]);
                pk.y = f2bf(acc[fm][fn][1]);
                pk.z = f2bf(acc[fm][fn][2]);
                pk.w = f2bf(acc[fm][fn][3]);
                *(ushort4*)(&C[(size_t)col * 512 + row0]) = pk;
            }
        }
}

// K1: blocks [0,64)   : LDS-tiled transpose w_proj -> wpT bf16
//     blocks [64,128) : w_attn V-slice -> wv bf16
//     blocks [128,256): partial sums of x (32-row chunks, float2 = 2 cols/thread)
__global__ __launch_bounds__(256) void k1_prep_partial(
    const float* __restrict__ x, const float* __restrict__ w_attn,
    const float* __restrict__ w_proj,
    unsigned short* __restrict__ wv, unsigned short* __restrict__ wpT,
    float* __restrict__ part)
{
    __shared__ float ls[64][65];
    const int bid = blockIdx.x, tid = threadIdx.x;

    if (bid < 64) {
        const int m0 = (bid >> 3) * 64;
        const int j0 = (bid & 7) * 64;
        const int rr = tid >> 4;
        const int c4 = (tid & 15) * 4;
        #pragma unroll
        for (int i = 0; i < 4; ++i) {
            float4 v = *(const float4*)(w_proj + (size_t)(m0 + rr + 16 * i) * 512 + j0 + c4);
            ls[rr + 16 * i][c4 + 0] = v.x;
            ls[rr + 16 * i][c4 + 1] = v.y;
            ls[rr + 16 * i][c4 + 2] = v.z;
            ls[rr + 16 * i][c4 + 3] = v.w;
        }
        __syncthreads();
        const int c    = tid >> 2;
        const int mgrp = (tid & 3) * 16;
        #pragma unroll
        for (int u = 0; u < 4; ++u) {
            const int m = mgrp + u * 4;
            ushort4 o;
            o.x = f2bf(ls[m + 0][c]);
            o.y = f2bf(ls[m + 1][c]);
            o.z = f2bf(ls[m + 2][c]);
            o.w = f2bf(ls[m + 3][c]);
            *(ushort4*)(wpT + (size_t)(j0 + c) * 512 + m0 + m) = o;
        }
    } else if (bid < 128) {
        const int bb = bid - 64;
        #pragma unroll
        for (int i = 0; i < 4; ++i) {
            const int flat = bb * 1024 + i * 256 + tid;
            const int ir = flat >> 7;
            const int m4 = (flat & 127) * 4;
            float4 v = *(const float4*)(w_attn + (size_t)ir * 1536 + 1024 + m4);
            ushort4 o;
            o.x = f2bf(v.x); o.y = f2bf(v.y); o.z = f2bf(v.z); o.w = f2bf(v.w);
            *(ushort4*)(wv + (size_t)ir * 512 + m4) = o;
        }
    } else {
        const int g  = bid - 128;             // 0..127: global 32-row chunk
        const int k0 = tid * 2;
        const float* p = x + (size_t)g * 32 * 512 + k0;
        float rx = 0.f, ry = 0.f;
        #pragma unroll 8
        for (int t = 0; t < 32; ++t) {
            float2 v = *(const float2*)(p + (size_t)t * 512);
            rx += v.x; ry += v.y;
        }
        *(float2*)(part + (size_t)g * 512 + k0) = make_float2(rx, ry);
    }
}

// K2: blocks [0,64)  : small GEMM wcT = (wv @ wp)^T
//     blocks [64,192): finalize (float2 masked fixed-trip prefix + packed bf16x2 stores)
__global__ __launch_bounds__(256) void k2_smallgemm_finalize(
    const float* __restrict__ x,
    const unsigned short* __restrict__ wv, const unsigned short* __restrict__ wpT,
    const float* __restrict__ part,
    unsigned short* __restrict__ wcT, unsigned short* __restrict__ s16)
{
    __shared__ __align__(16) unsigned short lds[2 * 16384];   // 64 KB
    const int bid = blockIdx.x, tid = threadIdx.x;

    if (bid < 64) {
        gemm_tile<1>(wv, wpT, wcT, lds, (bid >> 3) * 64, (bid & 7) * 64);
    } else {
        const int g  = bid - 64;              // 0..127: global 32-row chunk
        const int b  = g >> 6, ch = g & 63;
        const int k0 = tid * 2;
        // fixed-trip masked prefix, float2: 63 independent pipelined loads
        float rx = 0.f, ry = 0.f;
        #pragma unroll 8
        for (int cc = 0; cc < 63; ++cc) {
            float2 v = *(const float2*)(part + ((size_t)b * 64 + cc) * 512 + k0);
            rx += (cc < ch) ? v.x : 0.f;
            ry += (cc < ch) ? v.y : 0.f;
        }
        const float*    p = x   + (size_t)g * 32 * 512 + k0;
        unsigned short* q = s16 + (size_t)g * 32 * 512 + k0;
        #pragma unroll 8
        for (int t = 0; t < 32; ++t) {
            float2 v = *(const float2*)(p + (size_t)t * 512);
            rx += v.x; ry += v.y;
            const float inv = 1.0f / (float)(ch * 32 + t + 1);
            *(unsigned int*)(q + (size_t)t * 512) = pk2bf(rx * inv, ry * inv);
        }
    }
}

// K3 (r12 verbatim): y = s16 @ wcT^T, 64x64 tiles, BK=128, 512 blocks, XCD-chunked
__global__ __launch_bounds__(256) void k3_biggemm(
    const unsigned short* __restrict__ s16,
    const unsigned short* __restrict__ wcT,
    float* __restrict__ y)
{
    __shared__ __align__(16) unsigned short lds[2 * 16384];   // 64 KB
    const int bid  = blockIdx.x;            // 0..511
    const int xcd  = bid & 7;
    const int idx  = bid >> 3;              // 0..63
    const int vy   = xcd * 8 + (idx >> 3);  // m-tile 0..63
    const int vx   = idx & 7;               // n-tile 0..7
    gemm_tile<0>(s16, wcT, y, lds, vy * 64, vx * 64);
}

extern "C" void kernel_launch(void* const* d_in, const int* in_sizes, int n_in,
                              void* d_out, int out_size, void* d_ws, size_t ws_size,
                              hipStream_t stream)
{
    const float* x      = (const float*)d_in[0];   // (2,2048,512)
    const float* w_attn = (const float*)d_in[1];   // (512,1536); V = cols [1024,1536)
    const float* w_proj = (const float*)d_in[2];   // (512,512)
    float* y = (float*)d_out;

    unsigned short* wv  = (unsigned short*)d_ws;       // [512][512] bf16
    unsigned short* wpT = wv  + 512 * 512;             // [512][512] bf16 (w_proj^T)
    unsigned short* wcT = wpT + 512 * 512;             // [512][512] bf16 ((wv@wp)^T)
    unsigned short* s16 = wcT + 512 * 512;             // [4096][512] bf16
    float* part = (float*)(s16 + (size_t)4096 * 512);  // [2][64][512] f32

    k1_prep_partial<<<256, 256, 0, stream>>>(x, w_attn, w_proj, wv, wpT, part);
    k2_smallgemm_finalize<<<192, 256, 0, stream>>>(x, wv, wpT, part, wcT, s16);
    k3_biggemm<<<512, 256, 0, stream>>>(s16, wcT, y);
}

// Round 16
// 25.494 us; speedup vs baseline: 1.1788x; 1.0103x over previous
//
#include <hip/hip_runtime.h>

typedef __bf16 bf16x8 __attribute__((ext_vector_type(8)));
typedef float  f32x4  __attribute__((ext_vector_type(4)));

__device__ __forceinline__ unsigned short f2bf(float f) {
    unsigned int u = __float_as_uint(f);
    u += 0x7FFF + ((u >> 16) & 1);          // RNE
    return (unsigned short)(u >> 16);
}
__device__ __forceinline__ unsigned int pk2bf(float a, float b) {
    return (unsigned int)f2bf(a) | ((unsigned int)f2bf(b) << 16);
}

#define GLD_LDS16(gptr, lptr) \
    __builtin_amdgcn_global_load_lds((const __attribute__((address_space(1))) void*)(gptr), \
                                     (__attribute__((address_space(3))) void*)(lptr), 16, 0, 0)

// ---- r12-proven 64x64-tile bf16 GEMM body, BK=128, 2-deep prefetch + counted vmcnt.
// EPI=0: Cout=float[M][512] row-major. EPI=1: Cout=bf16 [512][512] transposed (C^T).
template<int EPI>
__device__ __forceinline__ void gemm_tile(const unsigned short* __restrict__ A,
                                          const unsigned short* __restrict__ Bt,
                                          void* __restrict__ Cout,
                                          unsigned short* lds,
                                          int bm, int bn)
{
    const int tid  = threadIdx.x;
    const int lane = tid & 63;
    const int w    = tid >> 6;
    const int wm   = w >> 1, wn = w & 1;
    const int arow = lane & 15;
    const int kg   = lane >> 4;

    const int srow   = tid >> 4;                 // row within 16-row group
    const int schunk = (tid & 15) ^ srow;        // inverse-swizzle on SOURCE
    const unsigned short* gA = A  + (size_t)(bm + srow) * 512 + schunk * 8;
    const unsigned short* gB = Bt + (size_t)(bn + srow) * 512 + schunk * 8;

    auto stage = [&](int buf, int kt) {
        unsigned short* la = lds + buf * 16384;
        unsigned short* lb = la + 8192;
        const int k0 = kt * 128;
        #pragma unroll
        for (int i = 0; i < 4; ++i) {
            GLD_LDS16(gA + (size_t)(i * 16) * 512 + k0, la + i * 2048 + w * 512);
            GLD_LDS16(gB + (size_t)(i * 16) * 512 + k0, lb + i * 2048 + w * 512);
        }
    };

    int offA[2][4], offB[2][4];
    #pragma unroll
    for (int f = 0; f < 2; ++f)
        #pragma unroll
        for (int kk = 0; kk < 4; ++kk) {
            offA[f][kk] = (wm * 32 + f * 16 + arow) * 256 + (((kk * 4 + kg) ^ arow) << 4);
            offB[f][kk] = (wn * 32 + f * 16 + arow) * 256 + (((kk * 4 + kg) ^ arow) << 4);
        }

    stage(0, 0);
    stage(1, 1);

    f32x4 acc[2][2] = {};
    #pragma unroll
    for (int kt = 0; kt < 4; ++kt) {
        const int buf = kt & 1;
        if (kt < 3) asm volatile("s_waitcnt vmcnt(8)" ::: "memory");
        else        asm volatile("s_waitcnt vmcnt(0)" ::: "memory");
        __builtin_amdgcn_s_barrier();
        const char* la = (const char*)(lds + buf * 16384);
        const char* lb = la + 16384;
        #pragma unroll
        for (int kk = 0; kk < 4; ++kk) {
            bf16x8 a0 = *(const bf16x8*)(la + offA[0][kk]);
            bf16x8 a1 = *(const bf16x8*)(la + offA[1][kk]);
            bf16x8 b0 = *(const bf16x8*)(lb + offB[0][kk]);
            bf16x8 b1 = *(const bf16x8*)(lb + offB[1][kk]);
            acc[0][0] = __builtin_amdgcn_mfma_f32_16x16x32_bf16(a0, b0, acc[0][0], 0, 0, 0);
            acc[0][1] = __builtin_amdgcn_mfma_f32_16x16x32_bf16(a0, b1, acc[0][1], 0, 0, 0);
            acc[1][0] = __builtin_amdgcn_mfma_f32_16x16x32_bf16(a1, b0, acc[1][0], 0, 0, 0);
            acc[1][1] = __builtin_amdgcn_mfma_f32_16x16x32_bf16(a1, b1, acc[1][1], 0, 0, 0);
        }
        __builtin_amdgcn_s_barrier();
        if (kt < 2) stage(buf, kt + 2);
    }

    #pragma unroll
    for (int fm = 0; fm < 2; ++fm)
        #pragma unroll
        for (int fn = 0; fn < 2; ++fn) {
            const int row0 = bm + wm * 32 + fm * 16 + kg * 4;
            const int col  = bn + wn * 32 + fn * 16 + arow;
            if (EPI == 0) {
                float* C = (float*)Cout;
                #pragma unroll
                for (int r = 0; r < 4; ++r)
                    C[(size_t)(row0 + r) * 512 + col] = acc[fm][fn][r];
            } else {
                unsigned short* C = (unsigned short*)Cout;   // C^T
                ushort4 pk;
                pk.x = f2bf(acc[fm][fn][0]);
                pk.y = f2bf(acc[fm][fn][1]);
                pk.z = f2bf(acc[fm][fn][2]);
                pk.w = f2bf(acc[fm][fn][3]);
                *(ushort4*)(&C[(size_t)col * 512 + row0]) = pk;
            }
        }
}

// K1: blocks [0,64)   : LDS-tiled transpose w_proj -> wpT bf16
//     blocks [64,128) : w_attn V-slice -> wv bf16
//     blocks [128,256): partial sums of x (32-row chunks, float2 = 2 cols/thread)
__global__ __launch_bounds__(256) void k1_prep_partial(
    const float* __restrict__ x, const float* __restrict__ w_attn,
    const float* __restrict__ w_proj,
    unsigned short* __restrict__ wv, unsigned short* __restrict__ wpT,
    float* __restrict__ part)
{
    __shared__ float ls[64][65];
    const int bid = blockIdx.x, tid = threadIdx.x;

    if (bid < 64) {
        const int m0 = (bid >> 3) * 64;
        const int j0 = (bid & 7) * 64;
        const int rr = tid >> 4;
        const int c4 = (tid & 15) * 4;
        #pragma unroll
        for (int i = 0; i < 4; ++i) {
            float4 v = *(const float4*)(w_proj + (size_t)(m0 + rr + 16 * i) * 512 + j0 + c4);
            ls[rr + 16 * i][c4 + 0] = v.x;
            ls[rr + 16 * i][c4 + 1] = v.y;
            ls[rr + 16 * i][c4 + 2] = v.z;
            ls[rr + 16 * i][c4 + 3] = v.w;
        }
        __syncthreads();
        const int c    = tid >> 2;
        const int mgrp = (tid & 3) * 16;
        #pragma unroll
        for (int u = 0; u < 4; ++u) {
            const int m = mgrp + u * 4;
            ushort4 o;
            o.x = f2bf(ls[m + 0][c]);
            o.y = f2bf(ls[m + 1][c]);
            o.z = f2bf(ls[m + 2][c]);
            o.w = f2bf(ls[m + 3][c]);
            *(ushort4*)(wpT + (size_t)(j0 + c) * 512 + m0 + m) = o;
        }
    } else if (bid < 128) {
        const int bb = bid - 64;
        #pragma unroll
        for (int i = 0; i < 4; ++i) {
            const int flat = bb * 1024 + i * 256 + tid;
            const int ir = flat >> 7;
            const int m4 = (flat & 127) * 4;
            float4 v = *(const float4*)(w_attn + (size_t)ir * 1536 + 1024 + m4);
            ushort4 o;
            o.x = f2bf(v.x); o.y = f2bf(v.y); o.z = f2bf(v.z); o.w = f2bf(v.w);
            *(ushort4*)(wv + (size_t)ir * 512 + m4) = o;
        }
    } else {
        const int g  = bid - 128;             // 0..127: global 32-row chunk
        const int k0 = tid * 2;
        const float* p = x + (size_t)g * 32 * 512 + k0;
        float rx = 0.f, ry = 0.f;
        #pragma unroll 8
        for (int t = 0; t < 32; ++t) {
            float2 v = *(const float2*)(p + (size_t)t * 512);
            rx += v.x; ry += v.y;
        }
        *(float2*)(part + (size_t)g * 512 + k0) = make_float2(rx, ry);
    }
}

// K2: blocks [0,64)  : small GEMM wcT = (wv @ wp)^T
//     blocks [64,192): finalize (float2 masked fixed-trip prefix + packed bf16x2 stores)
__global__ __launch_bounds__(256) void k2_smallgemm_finalize(
    const float* __restrict__ x,
    const unsigned short* __restrict__ wv, const unsigned short* __restrict__ wpT,
    const float* __restrict__ part,
    unsigned short* __restrict__ wcT, unsigned short* __restrict__ s16)
{
    __shared__ __align__(16) unsigned short lds[2 * 16384];   // 64 KB
    const int bid = blockIdx.x, tid = threadIdx.x;

    if (bid < 64) {
        gemm_tile<1>(wv, wpT, wcT, lds, (bid >> 3) * 64, (bid & 7) * 64);
    } else {
        const int g  = bid - 64;              // 0..127: global 32-row chunk
        const int b  = g >> 6, ch = g & 63;
        const int k0 = tid * 2;
        // fixed-trip masked prefix, float2: 63 independent pipelined loads
        float rx = 0.f, ry = 0.f;
        #pragma unroll 8
        for (int cc = 0; cc < 63; ++cc) {
            float2 v = *(const float2*)(part + ((size_t)b * 64 + cc) * 512 + k0);
            rx += (cc < ch) ? v.x : 0.f;
            ry += (cc < ch) ? v.y : 0.f;
        }
        const float*    p = x   + (size_t)g * 32 * 512 + k0;
        unsigned short* q = s16 + (size_t)g * 32 * 512 + k0;
        #pragma unroll 8
        for (int t = 0; t < 32; ++t) {
            float2 v = *(const float2*)(p + (size_t)t * 512);
            rx += v.x; ry += v.y;
            const float inv = 1.0f / (float)(ch * 32 + t + 1);
            *(unsigned int*)(q + (size_t)t * 512) = pk2bf(rx * inv, ry * inv);
        }
    }
}

// K3 (r12 verbatim): y = s16 @ wcT^T, 64x64 tiles, BK=128, 512 blocks, XCD-chunked
__global__ __launch_bounds__(256) void k3_biggemm(
    const unsigned short* __restrict__ s16,
    const unsigned short* __restrict__ wcT,
    float* __restrict__ y)
{
    __shared__ __align__(16) unsigned short lds[2 * 16384];   // 64 KB
    const int bid  = blockIdx.x;            // 0..511
    const int xcd  = bid & 7;
    const int idx  = bid >> 3;              // 0..63
    const int vy   = xcd * 8 + (idx >> 3);  // m-tile 0..63
    const int vx   = idx & 7;               // n-tile 0..7
    gemm_tile<0>(s16, wcT, y, lds, vy * 64, vx * 64);
}

extern "C" void kernel_launch(void* const* d_in, const int* in_sizes, int n_in,
                              void* d_out, int out_size, void* d_ws, size_t ws_size,
                              hipStream_t stream)
{
    const float* x      = (const float*)d_in[0];   // (2,2048,512)
    const float* w_attn = (const float*)d_in[1];   // (512,1536); V = cols [1024,1536)
    const float* w_proj = (const float*)d_in[2];   // (512,512)
    float* y = (float*)d_out;

    unsigned short* wv  = (unsigned short*)d_ws;       // [512][512] bf16
    unsigned short* wpT = wv  + 512 * 512;             // [512][512] bf16 (w_proj^T)
    unsigned short* wcT = wpT + 512 * 512;             // [512][512] bf16 ((wv@wp)^T)
    unsigned short* s16 = wcT + 512 * 512;             // [4096][512] bf16
    float* part = (float*)(s16 + (size_t)4096 * 512);  // [2][64][512] f32

    k1_prep_partial<<<256, 256, 0, stream>>>(x, w_attn, w_proj, wv, wpT, part);
    k2_smallgemm_finalize<<<192, 256, 0, stream>>>(x, wv, wpT, part, wcT, s16);
    k3_biggemm<<<512, 256, 0, stream>>>(s16, wcT, y);
}